// Round 7
// baseline (283.687 us; speedup 1.0000x reference)
//
#include <hip/hip_runtime.h>
#include <hip/hip_bf16.h>

#define NNODES   524288
#define NGRAPHS  4096
#define TPW      4     // 64-node tiles per wave; 256 blocks x 8 waves x 4 x 64 = NNODES
#define GS       12    // head LDS row stride (floats)

typedef __attribute__((ext_vector_type(8)))  short short8;
typedef __attribute__((ext_vector_type(4)))  float f32x4;
typedef __attribute__((ext_vector_type(16))) float f32x16;
typedef __attribute__((ext_vector_type(4)))  unsigned int u32x4;

static __device__ __forceinline__ unsigned short f2bf(float f) {
    __hip_bfloat16 h = __float2bfloat16(f);
    return *reinterpret_cast<unsigned short*>(&h);
}
static __device__ __forceinline__ unsigned pack_bf16(float lo, float hi) {
    return ((unsigned)f2bf(hi) << 16) | (unsigned)f2bf(lo);
}

// ---- one-time: bf16 weight transposes. wT[of][k] = w[k][of]; w0p[of][16]:
// k<4 = w0, k==4 = b0 (bias folded via B[k=4]=1.0), else 0 ----
__global__ __launch_bounds__(256) void prep_weights(
        const float* __restrict__ w0, const float* __restrict__ b0,
        const float* __restrict__ w1, const float* __restrict__ w2,
        unsigned short* __restrict__ w0p, unsigned short* __restrict__ w1T,
        unsigned short* __restrict__ w2T) {
    int e = blockIdx.x * 256 + threadIdx.x;
    if (e < 16384) {
        int k = e >> 7, n = e & 127;
        w1T[n * 128 + k] = f2bf(w1[e]);
    } else if (e < 32768) {
        int i = e - 16384;
        int k = i >> 7, n = i & 127;
        w2T[n * 128 + k] = f2bf(w2[i]);
    } else if (e < 34816) {
        int i = e - 32768;                 // w0p[128][16]
        int of = i >> 4, k = i & 15;
        unsigned short v = 0;
        if (k < 4)       v = f2bf(w0[k * 128 + of]);
        else if (k == 4) v = f2bf(b0[of]);
        w0p[i] = v;
    }
}

// ---- fused phi MLP: 8 waves/block, weights in LDS (frag-ordered),
//      in-register layer transitions (shfl half-exchange), zero hb ----
__global__ __launch_bounds__(512, 2) void phi_kernel(
        const float* __restrict__ x, const int* __restrict__ batch,
        const unsigned short* __restrict__ w0p,
        const unsigned short* __restrict__ w1T, const float* __restrict__ b1,
        const unsigned short* __restrict__ w2T, const float* __restrict__ b2,
        float* __restrict__ g) {
    // frag-ordered weights: entry eid=(mt*8+ks)*64+lane holds 8 shorts =
    // wT[(mt*32+(lane&31))*128 + ks*16 + (lane>>5)*8 .. +7]
    __shared__ __align__(16) short w1s[16384];   // 32 KB
    __shared__ __align__(16) short w2s[16384];   // 32 KB
    const int tid  = threadIdx.x;
    const int lane = tid & 63;
    const int wv   = tid >> 6;
    const int l31  = lane & 31;
    const int h    = lane >> 5;

    // ---- stage weights (once per block) ----
    #pragma unroll
    for (int i = 0; i < 4; ++i) {
        const int eid = i * 512 + tid;           // 0..2047
        const int ln  = eid & 63;
        const int mt  = eid >> 9;                // (eid>>6)>>3
        const int ks  = (eid >> 6) & 7;
        const size_t src = (size_t)(mt*32 + (ln & 31)) * 128 + ks*16 + (ln >> 5)*8;
        *reinterpret_cast<short8*>(&w1s[eid * 8]) =
            *reinterpret_cast<const short8*>(w1T + src);
        *reinterpret_cast<short8*>(&w2s[eid * 8]) =
            *reinterpret_cast<const short8*>(w2T + src);
    }

    // w0 frags (16 VGPRs) + b2 (registers) while staging lands
    short8 w0r[4];
    #pragma unroll
    for (int mt = 0; mt < 4; ++mt)
        w0r[mt] = *reinterpret_cast<const short8*>(w0p + (mt*32 + l31)*16 + h*8);
    float b2v[4];
    #pragma unroll
    for (int ntc = 0; ntc < 4; ++ntc) b2v[ntc] = b2[ntc*32 + l31];

    __syncthreads();   // the only barrier; weights read-only afterwards

    f32x16 acc[8];
    const f32x16 FZ = {};

    // swapped-C (col=node=l31, of in regs) -> A/B frag (outer=l31, k=8h+j)
    // frag elem j <- reg r=8(ks&1)+4h+(j&3) of lane-half (j>>2)
    auto convert = [&](short8 out[2][8], const float* bptr) {
        #pragma unroll
        for (int nt = 0; nt < 2; ++nt) {
            unsigned pk[4][8], oth[4][8];
            #pragma unroll
            for (int mt = 0; mt < 4; ++mt) {
                const f32x16 A = acc[mt*2 + nt];
                #pragma unroll
                for (int q = 0; q < 4; ++q) {
                    float4 bv = make_float4(0.f, 0.f, 0.f, 0.f);
                    if (bptr)
                        bv = *reinterpret_cast<const float4*>(bptr + mt*32 + 8*q + 4*h);
                    const float v0 = fmaxf(A[4*q+0] + bv.x, 0.f);
                    const float v1 = fmaxf(A[4*q+1] + bv.y, 0.f);
                    const float v2 = fmaxf(A[4*q+2] + bv.z, 0.f);
                    const float v3 = fmaxf(A[4*q+3] + bv.w, 0.f);
                    pk[mt][2*q]   = pack_bf16(v0, v1);
                    pk[mt][2*q+1] = pack_bf16(v2, v3);
                }
                #pragma unroll
                for (int p = 0; p < 8; ++p) oth[mt][p] = __shfl_xor(pk[mt][p], 32);
            }
            #pragma unroll
            for (int ks = 0; ks < 8; ++ks) {
                const int mt = ks >> 1, a4 = (ks & 1) * 4;
                u32x4 u;
                u[0] = h ? oth[mt][a4+2] : pk[mt][a4+0];
                u[1] = h ? oth[mt][a4+3] : pk[mt][a4+1];
                u[2] = h ? pk[mt][a4+2]  : oth[mt][a4+0];
                u[3] = h ? pk[mt][a4+3]  : oth[mt][a4+1];
                out[nt][ks] = __builtin_bit_cast(short8, u);
            }
        }
    };

    const int tile0 = (blockIdx.x * 8 + wv) * TPW;

    // prefetch tile-0 inputs
    float4 xv0 = *reinterpret_cast<const float4*>(x + (size_t)(tile0*64 + l31) * 4);
    float4 xv1 = *reinterpret_cast<const float4*>(x + (size_t)(tile0*64 + 32 + l31) * 4);
    int    gi  = batch[tile0*64 + lane];

    #pragma unroll 1
    for (int t = 0; t < TPW; ++t) {
        const int n0 = (tile0 + t) * 64;

        const int gp = __shfl_up(gi, 1);
        const unsigned long long mask = __ballot((lane == 0) || (gi != gp));

        // ---- layer 1 (swapped: A = w0r, B = x rows; b0 via B[k=4]=1) ----
        {
            short8 bf[2];
            const float4 xcur[2] = {xv0, xv1};
            #pragma unroll
            for (int nt = 0; nt < 2; ++nt) {
                short8 v = (short8){0,0,0,0,0,0,0,0};
                if (h == 0) {
                    v[0] = (short)f2bf(xcur[nt].x); v[1] = (short)f2bf(xcur[nt].y);
                    v[2] = (short)f2bf(xcur[nt].z); v[3] = (short)f2bf(xcur[nt].w);
                    v[4] = (short)0x3F80;   // 1.0 -> + b0 row
                }
                bf[nt] = v;
            }
            #pragma unroll
            for (int mt = 0; mt < 4; ++mt)
                #pragma unroll
                for (int nt = 0; nt < 2; ++nt)
                    acc[mt*2 + nt] = __builtin_amdgcn_mfma_f32_32x32x16_bf16(
                        w0r[mt], bf[nt], FZ, 0, 0, 0);
        }

        // prefetch next tile inputs
        float4 nxv0 = xv0, nxv1 = xv1; int ngi = gi;
        if (t + 1 < TPW) {
            const int nn0 = n0 + 64;
            nxv0 = *reinterpret_cast<const float4*>(x + (size_t)(nn0 + l31) * 4);
            nxv1 = *reinterpret_cast<const float4*>(x + (size_t)(nn0 + 32 + l31) * 4);
            ngi  = batch[nn0 + lane];
        }

        // ---- transition 1 (relu only; b0 folded) ----
        short8 bfr[2][8];
        convert(bfr, nullptr);

        // ---- layer 2 (swapped: A = w1 frags from LDS, B = bfr) ----
        #pragma unroll
        for (int ks = 0; ks < 8; ++ks) {
            short8 wf[4];
            #pragma unroll
            for (int mt = 0; mt < 4; ++mt)
                wf[mt] = *reinterpret_cast<const short8*>(
                    &w1s[((mt*8 + ks)*64 + lane) * 8]);
            #pragma unroll
            for (int mt = 0; mt < 4; ++mt)
                #pragma unroll
                for (int nt = 0; nt < 2; ++nt)
                    acc[mt*2 + nt] = __builtin_amdgcn_mfma_f32_32x32x16_bf16(
                        wf[mt], bfr[nt][ks], ks == 0 ? FZ : acc[mt*2 + nt], 0, 0, 0);
        }

        // ---- transition 2 (bias b1 + relu) ----
        short8 afr[2][8];
        convert(afr, b1);

        // ---- layer 3 (normal: A = afr, B = w2 frags from LDS) ----
        #pragma unroll
        for (int ks = 0; ks < 8; ++ks) {
            short8 wf[4];
            #pragma unroll
            for (int ntc = 0; ntc < 4; ++ntc)
                wf[ntc] = *reinterpret_cast<const short8*>(
                    &w2s[((ntc*8 + ks)*64 + lane) * 8]);
            #pragma unroll
            for (int mtn = 0; mtn < 2; ++mtn)
                #pragma unroll
                for (int ntc = 0; ntc < 4; ++ntc)
                    acc[mtn*4 + ntc] = __builtin_amdgcn_mfma_f32_32x32x16_bf16(
                        afr[mtn][ks], wf[ntc], ks == 0 ? FZ : acc[mtn*4 + ntc], 0, 0, 0);
        }

        // ---- epilogue: register segmented sum. C: col=of (l31), row=node ----
        unsigned long long rem = mask & (mask - 1);
        int s = 0;
        while (true) {
            const int e = rem ? (int)__builtin_ctzll(rem) : 64;
            const int grun = __shfl(gi, s);
            const float cnt = (float)(e - s);
            float* gdst = g + (size_t)grun * 128;
            #pragma unroll
            for (int ntc = 0; ntc < 4; ++ntc) {
                float val = 0.f;
                #pragma unroll
                for (int mtn = 0; mtn < 2; ++mtn) {
                    const f32x16 A = acc[mtn*4 + ntc];
                    #pragma unroll
                    for (int r = 0; r < 16; ++r) {
                        const int node = mtn*32 + (r & 3) + 8*(r >> 2) + 4*h;
                        const float inc = (node >= s && node < e) ? 1.f : 0.f;
                        val = fmaf(A[r], inc, val);
                    }
                }
                val += __shfl_xor(val, 32);
                if (h == 0)
                    atomicAdd(gdst + ntc*32 + l31, fmaf(cnt, b2v[ntc], val));
            }
            if (!rem) break;
            s = e;
            rem &= rem - 1;
        }

        xv0 = nxv0; xv1 = nxv1; gi = ngi;
    }
}

// ---- F head: fused 3 layers, 8 graphs/block, 512 blocks ----
__global__ __launch_bounds__(256) void head_kernel(
        const float* __restrict__ g,
        const float* __restrict__ fw0, const float* __restrict__ fb0,
        const float* __restrict__ fw1, const float* __restrict__ fb1,
        const float* __restrict__ fw2, const float* __restrict__ fb2,
        float* __restrict__ out) {
    __shared__ float gS[128 * GS];
    __shared__ float h1T[256 * GS];
    __shared__ float red[4][16];
    const int tid = threadIdx.x;
    const int g0  = blockIdx.x * 8;

    {
        const int gr = tid >> 5, k0 = (tid & 31) * 4;
        const float4 v = *reinterpret_cast<const float4*>(
            g + (size_t)(g0 + gr) * 128 + k0);
        gS[(k0+0)*GS + gr] = v.x; gS[(k0+1)*GS + gr] = v.y;
        gS[(k0+2)*GS + gr] = v.z; gS[(k0+3)*GS + gr] = v.w;
    }
    __syncthreads();

    float a1[8];
    #pragma unroll
    for (int i = 0; i < 8; ++i) a1[i] = 0.f;
    #pragma unroll 4
    for (int k = 0; k < 128; ++k) {
        const float w = fw0[k * 256 + tid];
        const f32x4 v0 = *reinterpret_cast<const f32x4*>(&gS[k*GS]);
        const f32x4 v1 = *reinterpret_cast<const f32x4*>(&gS[k*GS + 4]);
        #pragma unroll
        for (int j = 0; j < 4; ++j) {
            a1[j]     = fmaf(v0[j], w, a1[j]);
            a1[4 + j] = fmaf(v1[j], w, a1[4 + j]);
        }
    }
    {
        const float bb = fb0[tid];
        f32x4 s0, s1;
        #pragma unroll
        for (int j = 0; j < 4; ++j) {
            s0[j] = fmaxf(a1[j] + bb, 0.f);
            s1[j] = fmaxf(a1[4 + j] + bb, 0.f);
        }
        *reinterpret_cast<f32x4*>(&h1T[tid*GS])     = s0;
        *reinterpret_cast<f32x4*>(&h1T[tid*GS + 4]) = s1;
    }
    __syncthreads();

    float a2[8];
    #pragma unroll
    for (int i = 0; i < 8; ++i) a2[i] = 0.f;
    #pragma unroll 4
    for (int k = 0; k < 256; ++k) {
        const float w = fw1[k * 256 + tid];
        const f32x4 v0 = *reinterpret_cast<const f32x4*>(&h1T[k*GS]);
        const f32x4 v1 = *reinterpret_cast<const f32x4*>(&h1T[k*GS + 4]);
        #pragma unroll
        for (int j = 0; j < 4; ++j) {
            a2[j]     = fmaf(v0[j], w, a2[j]);
            a2[4 + j] = fmaf(v1[j], w, a2[4 + j]);
        }
    }

    float p[16];
    {
        const float bb  = fb1[tid];
        const float w2a = fw2[tid*2 + 0];
        const float w2b = fw2[tid*2 + 1];
        #pragma unroll
        for (int i = 0; i < 8; ++i) {
            const float h2 = fmaxf(a2[i] + bb, 0.f);
            p[i*2 + 0] = h2 * w2a;
            p[i*2 + 1] = h2 * w2b;
        }
    }
    #pragma unroll
    for (int i = 0; i < 16; ++i) {
        float v = p[i];
        v += __shfl_xor(v, 32); v += __shfl_xor(v, 16); v += __shfl_xor(v, 8);
        v += __shfl_xor(v, 4);  v += __shfl_xor(v, 2);  v += __shfl_xor(v, 1);
        p[i] = v;
    }
    if ((tid & 63) == 0) {
        #pragma unroll
        for (int i = 0; i < 16; ++i) red[tid >> 6][i] = p[i];
    }
    __syncthreads();
    if (tid < 16)
        out[g0*2 + tid] = red[0][tid] + red[1][tid] + red[2][tid] + red[3][tid]
                        + fb2[tid & 1];
}

extern "C" void kernel_launch(void* const* d_in, const int* in_sizes, int n_in,
                              void* d_out, int out_size, void* d_ws, size_t ws_size,
                              hipStream_t stream) {
    const float* x   = (const float*)d_in[0];
    // d_in[1] edge_index: mathematically dead (update() ignores aggr_out) — never read
    const int*   batch = (const int*)d_in[2];
    const float* w0  = (const float*)d_in[3];
    const float* b0  = (const float*)d_in[4];
    const float* w1  = (const float*)d_in[5];
    const float* b1  = (const float*)d_in[6];
    const float* w2  = (const float*)d_in[7];
    const float* b2  = (const float*)d_in[8];
    const float* fw0 = (const float*)d_in[9];
    const float* fb0 = (const float*)d_in[10];
    const float* fw1 = (const float*)d_in[11];
    const float* fb1 = (const float*)d_in[12];
    const float* fw2 = (const float*)d_in[13];
    const float* fb2 = (const float*)d_in[14];
    float* out = (float*)d_out;

    float* g = (float*)d_ws;                                        // 2 MB
    unsigned short* w1T = (unsigned short*)((char*)d_ws + (size_t)NGRAPHS * 128 * 4);
    unsigned short* w2T = w1T + 128 * 128;
    unsigned short* w0p = w2T + 128 * 128;                          // 4 KB

    (void)hipMemsetAsync(g, 0, (size_t)NGRAPHS * 128 * sizeof(float), stream);
    prep_weights<<<136, 256, 0, stream>>>(w0, b0, w1, w2, w0p, w1T, w2T);
    phi_kernel<<<NNODES / (64 * TPW * 8), 512, 0, stream>>>(
        x, batch, w0p, w1T, b1, w2T, b2, g);
    head_kernel<<<NGRAPHS / 8, 256, 0, stream>>>(g, fw0, fb0, fw1, fb1, fw2, fb2, out);
}

// Round 8
// 281.779 us; speedup vs baseline: 1.0068x; 1.0068x over previous
//
#include <hip/hip_runtime.h>
#include <hip/hip_bf16.h>

#define NNODES   524288
#define NGRAPHS  4096
#define TPW      4     // tiles/wave: 256 blocks x 8 waves x 4 x 64 = NNODES
#define GS       12    // head LDS row stride (floats)

typedef __attribute__((ext_vector_type(8)))  short short8;
typedef __attribute__((ext_vector_type(4)))  float f32x4;
typedef __attribute__((ext_vector_type(16))) float f32x16;
typedef __attribute__((ext_vector_type(4)))  unsigned int u32x4;

static __device__ __forceinline__ unsigned short f2bf(float f) {
    __hip_bfloat16 h = __float2bfloat16(f);
    return *reinterpret_cast<unsigned short*>(&h);
}
static __device__ __forceinline__ unsigned pack_bf16(float lo, float hi) {
    return ((unsigned)f2bf(hi) << 16) | (unsigned)f2bf(lo);
}

// ---- one-time: bf16 weight transposes. wT[of][k] = w[k][of]; w0p[of][16]:
// k<4 = w0, k==4 = b0 (bias folded via B[k=4]=1.0), else 0 ----
__global__ __launch_bounds__(256) void prep_weights(
        const float* __restrict__ w0, const float* __restrict__ b0,
        const float* __restrict__ w1, const float* __restrict__ w2,
        unsigned short* __restrict__ w0p, unsigned short* __restrict__ w1T,
        unsigned short* __restrict__ w2T) {
    int e = blockIdx.x * 256 + threadIdx.x;
    if (e < 16384) {
        int k = e >> 7, n = e & 127;
        w1T[n * 128 + k] = f2bf(w1[e]);
    } else if (e < 32768) {
        int i = e - 16384;
        int k = i >> 7, n = i & 127;
        w2T[n * 128 + k] = f2bf(w2[i]);
    } else if (e < 34816) {
        int i = e - 32768;                 // w0p[128][16]
        int of = i >> 4, k = i & 15;
        unsigned short v = 0;
        if (k < 4)       v = f2bf(w0[k * 128 + of]);
        else if (k == 4) v = f2bf(b0[of]);
        w0p[i] = v;
    }
}

// ---- fused phi MLP: 8 waves/block, LDS frag-ordered weights,
//      in-register shfl transitions, liveness-budgeted for 256 regs/wave ----
__global__ __launch_bounds__(512, 1) void phi_kernel(
        const float* __restrict__ x, const int* __restrict__ batch,
        const unsigned short* __restrict__ w0p,
        const unsigned short* __restrict__ w1T, const float* __restrict__ b1,
        const unsigned short* __restrict__ w2T, const float* __restrict__ b2,
        float* __restrict__ g) {
    // frag-ordered: entry eid=(mt*8+ks)*64+lane holds 8 shorts =
    // wT[(mt*32+(lane&31))*128 + ks*16 + (lane>>5)*8 .. +7]
    __shared__ __align__(16) short w1s[16384];   // 32 KB
    __shared__ __align__(16) short w2s[16384];   // 32 KB
    const int tid  = threadIdx.x;
    const int lane = tid & 63;
    const int wv   = tid >> 6;
    const int l31  = lane & 31;
    const int h    = lane >> 5;

    // ---- stage weights (once per block) ----
    #pragma unroll
    for (int i = 0; i < 4; ++i) {
        const int eid = i * 512 + tid;           // 0..2047
        const int ln  = eid & 63;
        const int mt  = eid >> 9;
        const int ks  = (eid >> 6) & 7;
        const size_t src = (size_t)(mt*32 + (ln & 31)) * 128 + ks*16 + (ln >> 5)*8;
        *reinterpret_cast<short8*>(&w1s[eid * 8]) =
            *reinterpret_cast<const short8*>(w1T + src);
        *reinterpret_cast<short8*>(&w2s[eid * 8]) =
            *reinterpret_cast<const short8*>(w2T + src);
    }

    short8 w0r[4];
    #pragma unroll
    for (int mt = 0; mt < 4; ++mt)
        w0r[mt] = *reinterpret_cast<const short8*>(w0p + (mt*32 + l31)*16 + h*8);
    float b2v[4];
    #pragma unroll
    for (int ntc = 0; ntc < 4; ++ntc) b2v[ntc] = b2[ntc*32 + l31];

    __syncthreads();   // only barrier; weights read-only afterwards

    f32x16 acc[8];
    const f32x16 FZ = {};
    short8 frag[2][8];   // shared by layer-2 B and layer-3 A (HW-verified mapping)

    // swapped-C (col=node=l31, of in regs) -> A/B frag (outer=l31, k=8h+j)
    // low-liveness: temps scoped per (mt,nt)
    auto convert = [&](const float* bptr) {
        #pragma unroll
        for (int mt = 0; mt < 4; ++mt) {
            #pragma unroll
            for (int nt = 0; nt < 2; ++nt) {
                const f32x16 A = acc[mt*2 + nt];
                unsigned pk[8], oth[8];
                #pragma unroll
                for (int q = 0; q < 4; ++q) {
                    float4 bv = make_float4(0.f, 0.f, 0.f, 0.f);
                    if (bptr)
                        bv = *reinterpret_cast<const float4*>(bptr + mt*32 + 8*q + 4*h);
                    const float v0 = fmaxf(A[4*q+0] + bv.x, 0.f);
                    const float v1 = fmaxf(A[4*q+1] + bv.y, 0.f);
                    const float v2 = fmaxf(A[4*q+2] + bv.z, 0.f);
                    const float v3 = fmaxf(A[4*q+3] + bv.w, 0.f);
                    pk[2*q]   = pack_bf16(v0, v1);
                    pk[2*q+1] = pack_bf16(v2, v3);
                }
                #pragma unroll
                for (int p = 0; p < 8; ++p) oth[p] = __shfl_xor(pk[p], 32);
                #pragma unroll
                for (int kk = 0; kk < 2; ++kk) {
                    const int a4 = kk * 4;
                    u32x4 u;
                    u[0] = h ? oth[a4+2] : pk[a4+0];
                    u[1] = h ? oth[a4+3] : pk[a4+1];
                    u[2] = h ? pk[a4+2]  : oth[a4+0];
                    u[3] = h ? pk[a4+3]  : oth[a4+1];
                    frag[nt][mt*2 + kk] = __builtin_bit_cast(short8, u);
                }
            }
        }
    };

    const int tile0 = (blockIdx.x * 8 + wv) * TPW;

    #pragma unroll 1
    for (int t = 0; t < TPW; ++t) {
        const int n0 = (tile0 + t) * 64;

        const int gi = batch[n0 + lane];
        const int gp = __shfl_up(gi, 1);
        const unsigned long long mask = __ballot((lane == 0) || (gi != gp));

        // ---- layer 1 (swapped: A = w0r, B = x rows; b0 via B[k=4]=1) ----
        {
            #pragma unroll
            for (int nt = 0; nt < 2; ++nt) {
                const float4 xv = *reinterpret_cast<const float4*>(
                    x + (size_t)(n0 + nt*32 + l31) * 4);
                short8 v = (short8){0,0,0,0,0,0,0,0};
                if (h == 0) {
                    v[0] = (short)f2bf(xv.x); v[1] = (short)f2bf(xv.y);
                    v[2] = (short)f2bf(xv.z); v[3] = (short)f2bf(xv.w);
                    v[4] = (short)0x3F80;   // 1.0 -> + b0 row
                }
                #pragma unroll
                for (int mt = 0; mt < 4; ++mt)
                    acc[mt*2 + nt] = __builtin_amdgcn_mfma_f32_32x32x16_bf16(
                        w0r[mt], v, FZ, 0, 0, 0);
            }
        }

        // ---- transition 1 (relu only; b0 folded) ----
        convert(nullptr);

        // ---- layer 2 (swapped: A = w1 frags from LDS, B = frag) ----
        #pragma unroll
        for (int ks = 0; ks < 8; ++ks) {
            short8 wf[4];
            #pragma unroll
            for (int mt = 0; mt < 4; ++mt)
                wf[mt] = *reinterpret_cast<const short8*>(
                    &w1s[((mt*8 + ks)*64 + lane) * 8]);
            #pragma unroll
            for (int mt = 0; mt < 4; ++mt)
                #pragma unroll
                for (int nt = 0; nt < 2; ++nt)
                    acc[mt*2 + nt] = __builtin_amdgcn_mfma_f32_32x32x16_bf16(
                        wf[mt], frag[nt][ks], ks == 0 ? FZ : acc[mt*2 + nt], 0, 0, 0);
        }

        // ---- transition 2 (bias b1 + relu) ----
        convert(b1);

        // ---- layer 3 (normal: A = frag, B = w2 frags from LDS) ----
        #pragma unroll
        for (int ks = 0; ks < 8; ++ks) {
            short8 wf[4];
            #pragma unroll
            for (int ntc = 0; ntc < 4; ++ntc)
                wf[ntc] = *reinterpret_cast<const short8*>(
                    &w2s[((ntc*8 + ks)*64 + lane) * 8]);
            #pragma unroll
            for (int mtn = 0; mtn < 2; ++mtn)
                #pragma unroll
                for (int ntc = 0; ntc < 4; ++ntc)
                    acc[mtn*4 + ntc] = __builtin_amdgcn_mfma_f32_32x32x16_bf16(
                        frag[mtn][ks], wf[ntc], ks == 0 ? FZ : acc[mtn*4 + ntc], 0, 0, 0);
        }

        // ---- epilogue: register segmented sum. C: col=of (l31), row=node ----
        unsigned long long rem = mask & (mask - 1);
        int s = 0;
        while (true) {
            const int e = rem ? (int)__builtin_ctzll(rem) : 64;
            const int grun = __shfl(gi, s);
            const float cnt = (float)(e - s);
            float* gdst = g + (size_t)grun * 128;
            #pragma unroll
            for (int ntc = 0; ntc < 4; ++ntc) {
                float val = 0.f;
                #pragma unroll
                for (int mtn = 0; mtn < 2; ++mtn) {
                    const f32x16 A = acc[mtn*4 + ntc];
                    #pragma unroll
                    for (int r = 0; r < 16; ++r) {
                        const int node = mtn*32 + (r & 3) + 8*(r >> 2) + 4*h;
                        const float inc = (node >= s && node < e) ? 1.f : 0.f;
                        val = fmaf(A[r], inc, val);
                    }
                }
                val += __shfl_xor(val, 32);
                if (h == 0)
                    atomicAdd(gdst + ntc*32 + l31, fmaf(cnt, b2v[ntc], val));
            }
            if (!rem) break;
            s = e;
            rem &= rem - 1;
        }
    }
}

// ---- F head: fused 3 layers, 8 graphs/block, 512 blocks ----
__global__ __launch_bounds__(256) void head_kernel(
        const float* __restrict__ g,
        const float* __restrict__ fw0, const float* __restrict__ fb0,
        const float* __restrict__ fw1, const float* __restrict__ fb1,
        const float* __restrict__ fw2, const float* __restrict__ fb2,
        float* __restrict__ out) {
    __shared__ float gS[128 * GS];
    __shared__ float h1T[256 * GS];
    __shared__ float red[4][16];
    const int tid = threadIdx.x;
    const int g0  = blockIdx.x * 8;

    {
        const int gr = tid >> 5, k0 = (tid & 31) * 4;
        const float4 v = *reinterpret_cast<const float4*>(
            g + (size_t)(g0 + gr) * 128 + k0);
        gS[(k0+0)*GS + gr] = v.x; gS[(k0+1)*GS + gr] = v.y;
        gS[(k0+2)*GS + gr] = v.z; gS[(k0+3)*GS + gr] = v.w;
    }
    __syncthreads();

    float a1[8];
    #pragma unroll
    for (int i = 0; i < 8; ++i) a1[i] = 0.f;
    #pragma unroll 4
    for (int k = 0; k < 128; ++k) {
        const float w = fw0[k * 256 + tid];
        const f32x4 v0 = *reinterpret_cast<const f32x4*>(&gS[k*GS]);
        const f32x4 v1 = *reinterpret_cast<const f32x4*>(&gS[k*GS + 4]);
        #pragma unroll
        for (int j = 0; j < 4; ++j) {
            a1[j]     = fmaf(v0[j], w, a1[j]);
            a1[4 + j] = fmaf(v1[j], w, a1[4 + j]);
        }
    }
    {
        const float bb = fb0[tid];
        f32x4 s0, s1;
        #pragma unroll
        for (int j = 0; j < 4; ++j) {
            s0[j] = fmaxf(a1[j] + bb, 0.f);
            s1[j] = fmaxf(a1[4 + j] + bb, 0.f);
        }
        *reinterpret_cast<f32x4*>(&h1T[tid*GS])     = s0;
        *reinterpret_cast<f32x4*>(&h1T[tid*GS + 4]) = s1;
    }
    __syncthreads();

    float a2[8];
    #pragma unroll
    for (int i = 0; i < 8; ++i) a2[i] = 0.f;
    #pragma unroll 4
    for (int k = 0; k < 256; ++k) {
        const float w = fw1[k * 256 + tid];
        const f32x4 v0 = *reinterpret_cast<const f32x4*>(&h1T[k*GS]);
        const f32x4 v1 = *reinterpret_cast<const f32x4*>(&h1T[k*GS + 4]);
        #pragma unroll
        for (int j = 0; j < 4; ++j) {
            a2[j]     = fmaf(v0[j], w, a2[j]);
            a2[4 + j] = fmaf(v1[j], w, a2[4 + j]);
        }
    }

    float p[16];
    {
        const float bb  = fb1[tid];
        const float w2a = fw2[tid*2 + 0];
        const float w2b = fw2[tid*2 + 1];
        #pragma unroll
        for (int i = 0; i < 8; ++i) {
            const float h2 = fmaxf(a2[i] + bb, 0.f);
            p[i*2 + 0] = h2 * w2a;
            p[i*2 + 1] = h2 * w2b;
        }
    }
    #pragma unroll
    for (int i = 0; i < 16; ++i) {
        float v = p[i];
        v += __shfl_xor(v, 32); v += __shfl_xor(v, 16); v += __shfl_xor(v, 8);
        v += __shfl_xor(v, 4);  v += __shfl_xor(v, 2);  v += __shfl_xor(v, 1);
        p[i] = v;
    }
    if ((tid & 63) == 0) {
        #pragma unroll
        for (int i = 0; i < 16; ++i) red[tid >> 6][i] = p[i];
    }
    __syncthreads();
    if (tid < 16)
        out[g0*2 + tid] = red[0][tid] + red[1][tid] + red[2][tid] + red[3][tid]
                        + fb2[tid & 1];
}

extern "C" void kernel_launch(void* const* d_in, const int* in_sizes, int n_in,
                              void* d_out, int out_size, void* d_ws, size_t ws_size,
                              hipStream_t stream) {
    const float* x   = (const float*)d_in[0];
    // d_in[1] edge_index: mathematically dead (update() ignores aggr_out) — never read
    const int*   batch = (const int*)d_in[2];
    const float* w0  = (const float*)d_in[3];
    const float* b0  = (const float*)d_in[4];
    const float* w1  = (const float*)d_in[5];
    const float* b1  = (const float*)d_in[6];
    const float* w2  = (const float*)d_in[7];
    const float* b2  = (const float*)d_in[8];
    const float* fw0 = (const float*)d_in[9];
    const float* fb0 = (const float*)d_in[10];
    const float* fw1 = (const float*)d_in[11];
    const float* fb1 = (const float*)d_in[12];
    const float* fw2 = (const float*)d_in[13];
    const float* fb2 = (const float*)d_in[14];
    float* out = (float*)d_out;

    float* g = (float*)d_ws;                                        // 2 MB
    unsigned short* w1T = (unsigned short*)((char*)d_ws + (size_t)NGRAPHS * 128 * 4);
    unsigned short* w2T = w1T + 128 * 128;
    unsigned short* w0p = w2T + 128 * 128;                          // 4 KB

    (void)hipMemsetAsync(g, 0, (size_t)NGRAPHS * 128 * sizeof(float), stream);
    prep_weights<<<136, 256, 0, stream>>>(w0, b0, w1, w2, w0p, w1T, w2T);
    phi_kernel<<<NNODES / (64 * TPW * 8), 512, 0, stream>>>(
        x, batch, w0p, w1T, b1, w2T, b2, g);
    head_kernel<<<NGRAPHS / 8, 256, 0, stream>>>(g, fw0, fb0, fw1, fb1, fw2, fb2, out);
}

// Round 9
// 265.133 us; speedup vs baseline: 1.0700x; 1.0628x over previous
//
#include <hip/hip_runtime.h>
#include <hip/hip_bf16.h>

#define NNODES   524288
#define NGRAPHS  4096
#define TPW      8     // tiles/wave: 256 blocks x 4 waves x 8 x 64 = NNODES
#define GS       12    // head LDS row stride (floats)

typedef __attribute__((ext_vector_type(8)))  short short8;
typedef __attribute__((ext_vector_type(4)))  float f32x4;
typedef __attribute__((ext_vector_type(16))) float f32x16;
typedef __attribute__((ext_vector_type(4)))  unsigned int u32x4;

static __device__ __forceinline__ unsigned short f2bf(float f) {
    __hip_bfloat16 h = __float2bfloat16(f);
    return *reinterpret_cast<unsigned short*>(&h);
}
static __device__ __forceinline__ unsigned pack_bf16(float lo, float hi) {
    return ((unsigned)f2bf(hi) << 16) | (unsigned)f2bf(lo);
}

// ---- one-time: bf16 weight transposes. wT[of][k] = w[k][of]; w0p[of][16]:
// k<4 = w0, k==4 = b0 (bias folded via B[k=4]=1.0), else 0 ----
__global__ __launch_bounds__(256) void prep_weights(
        const float* __restrict__ w0, const float* __restrict__ b0,
        const float* __restrict__ w1, const float* __restrict__ w2,
        unsigned short* __restrict__ w0p, unsigned short* __restrict__ w1T,
        unsigned short* __restrict__ w2T) {
    int e = blockIdx.x * 256 + threadIdx.x;
    if (e < 16384) {
        int k = e >> 7, n = e & 127;
        w1T[n * 128 + k] = f2bf(w1[e]);
    } else if (e < 32768) {
        int i = e - 16384;
        int k = i >> 7, n = i & 127;
        w2T[n * 128 + k] = f2bf(w2[i]);
    } else if (e < 34816) {
        int i = e - 32768;                 // w0p[128][16]
        int of = i >> 4, k = i & 15;
        unsigned short v = 0;
        if (k < 4)       v = f2bf(w0[k * 128 + of]);
        else if (k == 4) v = f2bf(b0[of]);
        w0p[i] = v;
    }
}

// ---- fused phi MLP: 4 waves/block (1 wave/SIMD -> 512-reg budget, no spill),
//      LDS frag-ordered weights, in-register shfl transitions ----
__global__ __launch_bounds__(256, 1) void phi_kernel(
        const float* __restrict__ x, const int* __restrict__ batch,
        const unsigned short* __restrict__ w0p,
        const unsigned short* __restrict__ w1T, const float* __restrict__ b1,
        const unsigned short* __restrict__ w2T, const float* __restrict__ b2,
        float* __restrict__ g) {
    // frag-ordered: entry eid=(mt*8+ks)*64+lane holds 8 shorts =
    // wT[(mt*32+(lane&31))*128 + ks*16 + (lane>>5)*8 .. +7]
    __shared__ __align__(16) short w1s[16384];   // 32 KB
    __shared__ __align__(16) short w2s[16384];   // 32 KB
    const int tid  = threadIdx.x;
    const int lane = tid & 63;
    const int wv   = tid >> 6;
    const int l31  = lane & 31;
    const int h    = lane >> 5;

    // ---- stage weights (once per block) ----
    #pragma unroll
    for (int i = 0; i < 8; ++i) {
        const int eid = i * 256 + tid;           // 0..2047
        const int ln  = eid & 63;
        const int mt  = eid >> 9;
        const int ks  = (eid >> 6) & 7;
        const size_t src = (size_t)(mt*32 + (ln & 31)) * 128 + ks*16 + (ln >> 5)*8;
        *reinterpret_cast<short8*>(&w1s[eid * 8]) =
            *reinterpret_cast<const short8*>(w1T + src);
        *reinterpret_cast<short8*>(&w2s[eid * 8]) =
            *reinterpret_cast<const short8*>(w2T + src);
    }

    short8 w0r[4];
    #pragma unroll
    for (int mt = 0; mt < 4; ++mt)
        w0r[mt] = *reinterpret_cast<const short8*>(w0p + (mt*32 + l31)*16 + h*8);
    float b2v[4];
    #pragma unroll
    for (int ntc = 0; ntc < 4; ++ntc) b2v[ntc] = b2[ntc*32 + l31];

    __syncthreads();   // only barrier; weights read-only afterwards

    f32x16 acc[8];
    const f32x16 FZ = {};
    short8 frag[2][8];   // shared by layer-2 B and layer-3 A (HW-verified mapping)

    // swapped-C (col=node=l31, of in regs) -> A/B frag (outer=l31, k=8h+j)
    auto convert = [&](const float* bptr) {
        #pragma unroll
        for (int mt = 0; mt < 4; ++mt) {
            #pragma unroll
            for (int nt = 0; nt < 2; ++nt) {
                const f32x16 A = acc[mt*2 + nt];
                unsigned pk[8], oth[8];
                #pragma unroll
                for (int q = 0; q < 4; ++q) {
                    float4 bv = make_float4(0.f, 0.f, 0.f, 0.f);
                    if (bptr)
                        bv = *reinterpret_cast<const float4*>(bptr + mt*32 + 8*q + 4*h);
                    const float v0 = fmaxf(A[4*q+0] + bv.x, 0.f);
                    const float v1 = fmaxf(A[4*q+1] + bv.y, 0.f);
                    const float v2 = fmaxf(A[4*q+2] + bv.z, 0.f);
                    const float v3 = fmaxf(A[4*q+3] + bv.w, 0.f);
                    pk[2*q]   = pack_bf16(v0, v1);
                    pk[2*q+1] = pack_bf16(v2, v3);
                }
                #pragma unroll
                for (int p = 0; p < 8; ++p) oth[p] = __shfl_xor(pk[p], 32);
                #pragma unroll
                for (int kk = 0; kk < 2; ++kk) {
                    const int a4 = kk * 4;
                    u32x4 u;
                    u[0] = h ? oth[a4+2] : pk[a4+0];
                    u[1] = h ? oth[a4+3] : pk[a4+1];
                    u[2] = h ? pk[a4+2]  : oth[a4+0];
                    u[3] = h ? pk[a4+3]  : oth[a4+1];
                    frag[nt][mt*2 + kk] = __builtin_bit_cast(short8, u);
                }
            }
        }
    };

    const int tile0 = (blockIdx.x * 4 + wv) * TPW;

    // prefetch tile-0 inputs
    float4 xv0 = *reinterpret_cast<const float4*>(x + (size_t)(tile0*64 + l31) * 4);
    float4 xv1 = *reinterpret_cast<const float4*>(x + (size_t)(tile0*64 + 32 + l31) * 4);
    int    gi  = batch[tile0*64 + lane];

    #pragma unroll 1
    for (int t = 0; t < TPW; ++t) {
        const int n0 = (tile0 + t) * 64;

        const int gp = __shfl_up(gi, 1);
        const unsigned long long mask = __ballot((lane == 0) || (gi != gp));

        // ---- layer 1 (swapped: A = w0r, B = x rows; b0 via B[k=4]=1) ----
        {
            const float4 xcur[2] = {xv0, xv1};
            #pragma unroll
            for (int nt = 0; nt < 2; ++nt) {
                short8 v = (short8){0,0,0,0,0,0,0,0};
                if (h == 0) {
                    v[0] = (short)f2bf(xcur[nt].x); v[1] = (short)f2bf(xcur[nt].y);
                    v[2] = (short)f2bf(xcur[nt].z); v[3] = (short)f2bf(xcur[nt].w);
                    v[4] = (short)0x3F80;   // 1.0 -> + b0 row
                }
                #pragma unroll
                for (int mt = 0; mt < 4; ++mt)
                    acc[mt*2 + nt] = __builtin_amdgcn_mfma_f32_32x32x16_bf16(
                        w0r[mt], v, FZ, 0, 0, 0);
            }
        }

        // prefetch next tile inputs (hidden behind layers 1-3 compute)
        float4 nxv0 = xv0, nxv1 = xv1; int ngi = gi;
        if (t + 1 < TPW) {
            const int nn0 = n0 + 64;
            nxv0 = *reinterpret_cast<const float4*>(x + (size_t)(nn0 + l31) * 4);
            nxv1 = *reinterpret_cast<const float4*>(x + (size_t)(nn0 + 32 + l31) * 4);
            ngi  = batch[nn0 + lane];
        }

        // ---- transition 1 (relu only; b0 folded) ----
        convert(nullptr);

        // ---- layer 2 (swapped: A = w1 frags from LDS, B = frag) ----
        #pragma unroll
        for (int ks = 0; ks < 8; ++ks) {
            short8 wf[4];
            #pragma unroll
            for (int mt = 0; mt < 4; ++mt)
                wf[mt] = *reinterpret_cast<const short8*>(
                    &w1s[((mt*8 + ks)*64 + lane) * 8]);
            #pragma unroll
            for (int mt = 0; mt < 4; ++mt)
                #pragma unroll
                for (int nt = 0; nt < 2; ++nt)
                    acc[mt*2 + nt] = __builtin_amdgcn_mfma_f32_32x32x16_bf16(
                        wf[mt], frag[nt][ks], ks == 0 ? FZ : acc[mt*2 + nt], 0, 0, 0);
        }

        // ---- transition 2 (bias b1 + relu) ----
        convert(b1);

        // ---- layer 3 (normal: A = frag, B = w2 frags from LDS) ----
        #pragma unroll
        for (int ks = 0; ks < 8; ++ks) {
            short8 wf[4];
            #pragma unroll
            for (int ntc = 0; ntc < 4; ++ntc)
                wf[ntc] = *reinterpret_cast<const short8*>(
                    &w2s[((ntc*8 + ks)*64 + lane) * 8]);
            #pragma unroll
            for (int mtn = 0; mtn < 2; ++mtn)
                #pragma unroll
                for (int ntc = 0; ntc < 4; ++ntc)
                    acc[mtn*4 + ntc] = __builtin_amdgcn_mfma_f32_32x32x16_bf16(
                        frag[mtn][ks], wf[ntc], ks == 0 ? FZ : acc[mtn*4 + ntc], 0, 0, 0);
        }

        // ---- epilogue: register segmented sum. C: col=of (l31), row=node ----
        unsigned long long rem = mask & (mask - 1);
        int s = 0;
        while (true) {
            const int e = rem ? (int)__builtin_ctzll(rem) : 64;
            const int grun = __shfl(gi, s);
            const float cnt = (float)(e - s);
            float* gdst = g + (size_t)grun * 128;
            #pragma unroll
            for (int ntc = 0; ntc < 4; ++ntc) {
                float val = 0.f;
                #pragma unroll
                for (int mtn = 0; mtn < 2; ++mtn) {
                    const f32x16 A = acc[mtn*4 + ntc];
                    #pragma unroll
                    for (int r = 0; r < 16; ++r) {
                        const int node = mtn*32 + (r & 3) + 8*(r >> 2) + 4*h;
                        const float inc = (node >= s && node < e) ? 1.f : 0.f;
                        val = fmaf(A[r], inc, val);
                    }
                }
                val += __shfl_xor(val, 32);
                if (h == 0)
                    atomicAdd(gdst + ntc*32 + l31, fmaf(cnt, b2v[ntc], val));
            }
            if (!rem) break;
            s = e;
            rem &= rem - 1;
        }

        xv0 = nxv0; xv1 = nxv1; gi = ngi;
    }
}

// ---- F head: fused 3 layers, 8 graphs/block, 512 blocks ----
__global__ __launch_bounds__(256) void head_kernel(
        const float* __restrict__ g,
        const float* __restrict__ fw0, const float* __restrict__ fb0,
        const float* __restrict__ fw1, const float* __restrict__ fb1,
        const float* __restrict__ fw2, const float* __restrict__ fb2,
        float* __restrict__ out) {
    __shared__ float gS[128 * GS];
    __shared__ float h1T[256 * GS];
    __shared__ float red[4][16];
    const int tid = threadIdx.x;
    const int g0  = blockIdx.x * 8;

    {
        const int gr = tid >> 5, k0 = (tid & 31) * 4;
        const float4 v = *reinterpret_cast<const float4*>(
            g + (size_t)(g0 + gr) * 128 + k0);
        gS[(k0+0)*GS + gr] = v.x; gS[(k0+1)*GS + gr] = v.y;
        gS[(k0+2)*GS + gr] = v.z; gS[(k0+3)*GS + gr] = v.w;
    }
    __syncthreads();

    float a1[8];
    #pragma unroll
    for (int i = 0; i < 8; ++i) a1[i] = 0.f;
    #pragma unroll 4
    for (int k = 0; k < 128; ++k) {
        const float w = fw0[k * 256 + tid];
        const f32x4 v0 = *reinterpret_cast<const f32x4*>(&gS[k*GS]);
        const f32x4 v1 = *reinterpret_cast<const f32x4*>(&gS[k*GS + 4]);
        #pragma unroll
        for (int j = 0; j < 4; ++j) {
            a1[j]     = fmaf(v0[j], w, a1[j]);
            a1[4 + j] = fmaf(v1[j], w, a1[4 + j]);
        }
    }
    {
        const float bb = fb0[tid];
        f32x4 s0, s1;
        #pragma unroll
        for (int j = 0; j < 4; ++j) {
            s0[j] = fmaxf(a1[j] + bb, 0.f);
            s1[j] = fmaxf(a1[4 + j] + bb, 0.f);
        }
        *reinterpret_cast<f32x4*>(&h1T[tid*GS])     = s0;
        *reinterpret_cast<f32x4*>(&h1T[tid*GS + 4]) = s1;
    }
    __syncthreads();

    float a2[8];
    #pragma unroll
    for (int i = 0; i < 8; ++i) a2[i] = 0.f;
    #pragma unroll 4
    for (int k = 0; k < 256; ++k) {
        const float w = fw1[k * 256 + tid];
        const f32x4 v0 = *reinterpret_cast<const f32x4*>(&h1T[k*GS]);
        const f32x4 v1 = *reinterpret_cast<const f32x4*>(&h1T[k*GS + 4]);
        #pragma unroll
        for (int j = 0; j < 4; ++j) {
            a2[j]     = fmaf(v0[j], w, a2[j]);
            a2[4 + j] = fmaf(v1[j], w, a2[4 + j]);
        }
    }

    float p[16];
    {
        const float bb  = fb1[tid];
        const float w2a = fw2[tid*2 + 0];
        const float w2b = fw2[tid*2 + 1];
        #pragma unroll
        for (int i = 0; i < 8; ++i) {
            const float h2 = fmaxf(a2[i] + bb, 0.f);
            p[i*2 + 0] = h2 * w2a;
            p[i*2 + 1] = h2 * w2b;
        }
    }
    #pragma unroll
    for (int i = 0; i < 16; ++i) {
        float v = p[i];
        v += __shfl_xor(v, 32); v += __shfl_xor(v, 16); v += __shfl_xor(v, 8);
        v += __shfl_xor(v, 4);  v += __shfl_xor(v, 2);  v += __shfl_xor(v, 1);
        p[i] = v;
    }
    if ((tid & 63) == 0) {
        #pragma unroll
        for (int i = 0; i < 16; ++i) red[tid >> 6][i] = p[i];
    }
    __syncthreads();
    if (tid < 16)
        out[g0*2 + tid] = red[0][tid] + red[1][tid] + red[2][tid] + red[3][tid]
                        + fb2[tid & 1];
}

extern "C" void kernel_launch(void* const* d_in, const int* in_sizes, int n_in,
                              void* d_out, int out_size, void* d_ws, size_t ws_size,
                              hipStream_t stream) {
    const float* x   = (const float*)d_in[0];
    // d_in[1] edge_index: mathematically dead (update() ignores aggr_out) — never read
    const int*   batch = (const int*)d_in[2];
    const float* w0  = (const float*)d_in[3];
    const float* b0  = (const float*)d_in[4];
    const float* w1  = (const float*)d_in[5];
    const float* b1  = (const float*)d_in[6];
    const float* w2  = (const float*)d_in[7];
    const float* b2  = (const float*)d_in[8];
    const float* fw0 = (const float*)d_in[9];
    const float* fb0 = (const float*)d_in[10];
    const float* fw1 = (const float*)d_in[11];
    const float* fb1 = (const float*)d_in[12];
    const float* fw2 = (const float*)d_in[13];
    const float* fb2 = (const float*)d_in[14];
    float* out = (float*)d_out;

    float* g = (float*)d_ws;                                        // 2 MB
    unsigned short* w1T = (unsigned short*)((char*)d_ws + (size_t)NGRAPHS * 128 * 4);
    unsigned short* w2T = w1T + 128 * 128;
    unsigned short* w0p = w2T + 128 * 128;                          // 4 KB

    (void)hipMemsetAsync(g, 0, (size_t)NGRAPHS * 128 * sizeof(float), stream);
    prep_weights<<<136, 256, 0, stream>>>(w0, b0, w1, w2, w0p, w1T, w2T);
    phi_kernel<<<NNODES / (64 * TPW * 4), 256, 0, stream>>>(
        x, batch, w0p, w1T, b1, w2T, b2, g);
    head_kernel<<<NGRAPHS / 8, 256, 0, stream>>>(g, fw0, fb0, fw1, fb1, fw2, fb2, out);
}